// Round 5
// baseline (330.408 us; speedup 1.0000x reference)
//
#include <hip/hip_runtime.h>
#include <hip/hip_bf16.h>

#define D_DIM 256
#define K_CODES 1024
#define HW 1024
#define N_VEC 32768
#define N_ELEM 8388608ull

typedef __attribute__((ext_vector_type(8))) short bf16x8;
typedef __attribute__((ext_vector_type(4))) float f32x4;
typedef __attribute__((ext_vector_type(2))) float f32x2;

static __device__ __forceinline__ unsigned short f2bf(float x) {
    union { __hip_bfloat16 h; unsigned short u; } cvt;
    cvt.h = __float2bfloat16(x);
    return cvt.u;
}

// ---------------------------------------------------------------------------
// Kernel A (fused prep): codebook -> bf16 B-fragment order + codebook norms
// + zero counts/lossacc. 128 blocks x 256.
// ---------------------------------------------------------------------------
__global__ __launch_bounds__(256) void prep_kernel(const float* __restrict__ cb,
                                                   unsigned short* __restrict__ cbb,
                                                   float* __restrict__ cnorm,
                                                   int* __restrict__ counts,
                                                   float* __restrict__ lossacc) {
    int slot = blockIdx.x * 256 + threadIdx.x;  // 0 .. 32767
    // --- cbprep: fragment-order bf16 codebook ---
    {
        int lane = slot & 63;
        int dchunk = (slot >> 6) & 7;
        int ktile = slot >> 9;
        int code = ktile * 16 + (lane & 15);
        int d0 = dchunk * 32 + (lane >> 4) * 8;
        const float4* src = (const float4*)(cb + (size_t)code * D_DIM + d0);
        float4 v0 = src[0], v1 = src[1];
        int4 o;
        o.x = f2bf(v0.x) | ((unsigned)f2bf(v0.y) << 16);
        o.y = f2bf(v0.z) | ((unsigned)f2bf(v0.w) << 16);
        o.z = f2bf(v1.x) | ((unsigned)f2bf(v1.y) << 16);
        o.w = f2bf(v1.z) | ((unsigned)f2bf(v1.w) << 16);
        *(int4*)(cbb + (size_t)slot * 8) = o;
    }
    // --- cnorm (8 lanes per code) + zero counts/lossacc ---
    if (slot < 8192) {
        if (slot < K_CODES) counts[slot] = 0;
        if (slot == K_CODES) lossacc[0] = 0.f;
        int k = slot >> 3;
        int part = slot & 7;
        const float4* row = (const float4*)(cb + (size_t)k * D_DIM + part * 32);
        float s = 0.f;
#pragma unroll
        for (int i = 0; i < 8; i++) {
            float4 v = row[i];
            s = fmaf(v.x, v.x, s);
            s = fmaf(v.y, v.y, s);
            s = fmaf(v.z, v.z, s);
            s = fmaf(v.w, v.w, s);
        }
        s += __shfl_xor(s, 1);
        s += __shfl_xor(s, 2);
        s += __shfl_xor(s, 4);
        if (part == 0) cnorm[k] = s;
    }
}

// ---------------------------------------------------------------------------
// Kernel B (FUSED): argmin via bf16 MFMA + quantize/STE + loss + one-hot enc.
// *** ROUND 4 (retry): INSTRUMENTATION BUILD ***
// Launched TWICE. PASS=0 is the real kernel (identical to round 3). PASS=1
// repeats ALL memory work idempotently (out/enc rewritten with identical
// values) but skips the non-idempotent scalar side effects (indices write,
// counts atomicAdd, lossacc atomicAdd). dur_us(R4) - dur_us(R3) measures
// T(fused_vq) in-band, since the occluded top-5 profile gives no per-kernel
// attribution. asm-keepalive on the loss value prevents DCE of the fmaf
// chain in PASS=1 (guide rule #17).
// ---------------------------------------------------------------------------
template <int PASS>
__global__ __launch_bounds__(256, 2) void fused_vq(const float* __restrict__ z,
                                                   const unsigned short* __restrict__ cbb,
                                                   const float* __restrict__ cnorm,
                                                   const float* __restrict__ cb,
                                                   int* __restrict__ indices,
                                                   int* __restrict__ counts,
                                                   float* __restrict__ out,
                                                   float* __restrict__ enc,
                                                   float* __restrict__ lossacc) {
    __shared__ unsigned short Bbuf[2][4 * 8 * 64 * 8];  // 2 x 32 KB
    __shared__ int bk[64];
    __shared__ float wsum[4];
    const int t = threadIdx.x;
    const int lane = t & 63;
    const int w = t >> 6;                // wave 0..3
    const int nt0 = blockIdx.x * 4 + w;  // wave owns ONE ntile
    const int row = lane & 15;
    const int dq = (lane >> 4) * 8;
    const int n = nt0 * 16 + row;  // this lane's z row
    const int b = n >> 10;
    const int hw = n & (HW - 1);

    // ---- prologue: load z f32 (kept in regs) + pack bf16 A fragments ----
    float zf[8][8];
    bf16x8 Ar[8];
#pragma unroll
    for (int dc = 0; dc < 8; dc++) {
        const float* src = z + (((size_t)(b * D_DIM + dc * 32 + dq)) << 10) + hw;
        union { bf16x8 v; unsigned short u[8]; } pk;
#pragma unroll
        for (int j = 0; j < 8; j++) {
            zf[dc][j] = __builtin_nontemporal_load(src + ((size_t)j << 10));
            pk.u[j] = f2bf(zf[dc][j]);
        }
        Ar[dc] = pk.v;
    }

    // ---- async stage of chunk 0 ----
    {
        const unsigned int* g = (const unsigned int*)cbb;
        unsigned int* l = (unsigned int*)Bbuf[0];
#pragma unroll
        for (int p = 0; p < 8; p++) {
            int off = (p * 256 + t) * 4;
            __builtin_amdgcn_global_load_lds(
                (const __attribute__((address_space(1))) unsigned int*)(g + off),
                (__attribute__((address_space(3))) unsigned int*)(l + off), 16, 0, 0);
        }
    }

    float bestd[4];
    int bestk[4];
#pragma unroll
    for (int r = 0; r < 4; r++) { bestd[r] = 3.4e38f; bestk[r] = 0; }

    const int col = lane & 15;
    for (int c = 0; c < 16; c++) {
        const int cur = c & 1;
        __syncthreads();  // drains vmcnt -> Bbuf[cur] ready; all waves done with other buf
        if (c < 15) {
            const unsigned int* g = (const unsigned int*)(cbb + (size_t)(c + 1) * 16384);
            unsigned int* l = (unsigned int*)Bbuf[cur ^ 1];
#pragma unroll
            for (int p = 0; p < 8; p++) {
                int off = (p * 256 + t) * 4;
                __builtin_amdgcn_global_load_lds(
                    (const __attribute__((address_space(1))) unsigned int*)(g + off),
                    (__attribute__((address_space(3))) unsigned int*)(l + off), 16, 0, 0);
            }
        }
        const unsigned short* Bb = Bbuf[cur];
#pragma unroll
        for (int half = 0; half < 2; half++) {  // 2 ktiles at a time, bb = 64 VGPR
            bf16x8 bb[2][8];
#pragma unroll
            for (int kt2 = 0; kt2 < 2; kt2++)
#pragma unroll
                for (int dc = 0; dc < 8; dc++)
                    bb[kt2][dc] = *(const bf16x8*)
                        &Bb[(((half * 2 + kt2) * 8 + dc) * 64 + lane) * 8];
            f32x4 acc[2];
#pragma unroll
            for (int kt2 = 0; kt2 < 2; kt2++) acc[kt2] = (f32x4){0.f, 0.f, 0.f, 0.f};
#pragma unroll
            for (int dc = 0; dc < 8; dc++)
#pragma unroll
                for (int kt2 = 0; kt2 < 2; kt2++)
                    acc[kt2] = __builtin_amdgcn_mfma_f32_16x16x32_bf16(
                        Ar[dc], bb[kt2][dc], acc[kt2], 0, 0, 0);
            // running best (k ascending => first-min tiebreak)
#pragma unroll
            for (int kt2 = 0; kt2 < 2; kt2++) {
                int k = (c * 4 + half * 2 + kt2) * 16 + col;
                float cn = cnorm[k];
#pragma unroll
                for (int r = 0; r < 4; r++) {
                    float sc = fmaf(-2.0f, acc[kt2][r], cn);
                    if (sc < bestd[r]) { bestd[r] = sc; bestk[r] = k; }
                }
            }
        }
    }

    // ---- reduce across the 16 columns; stash winning codes in LDS ----
#pragma unroll
    for (int r = 0; r < 4; r++) {
        float dd = bestd[r];
        int kk = bestk[r];
#pragma unroll
        for (int off = 8; off >= 1; off >>= 1) {
            float d2 = __shfl_xor(dd, off);
            int k2 = __shfl_xor(kk, off);
            if (d2 < dd || (d2 == dd && k2 < kk)) { dd = d2; kk = k2; }
        }
        if ((lane & 15) == 0) {
            int nloc = w * 16 + (lane >> 4) * 4 + r;  // block-local n
            bk[nloc] = kk;
            if constexpr (PASS == 0) {
                indices[blockIdx.x * 64 + nloc] = kk;
                atomicAdd(&counts[kk], 1);
            }
        }
    }
    __syncthreads();  // bk visible to all waves

    // ---- epilogue 1: quantize + STE output + loss (z still in VGPRs) ----
    const int mycode = bk[w * 16 + row];
    const float* crow = cb + (size_t)mycode * D_DIM;
    float* obase = out + (((size_t)b * D_DIM) << 10) + hw;
    float ls = 0.f;
#pragma unroll
    for (int dc = 0; dc < 8; dc++)
#pragma unroll
        for (int j = 0; j < 8; j++) {
            int d = dc * 32 + dq + j;
            float q = crow[d];
            float zv = zf[dc][j];
            float e = q - zv;
            __builtin_nontemporal_store(zv + e, obase + ((size_t)d << 10));
            ls = fmaf(e, e, ls);
        }

    // ---- epilogue 2: one-hot enc rows (skip rows <192: cbb alias, deferred) ----
    const int n0 = blockIdx.x * 64;
    if (n0 >= 192) {
#pragma unroll 4
        for (int j = 0; j < 64; j++) {
            int idx = bk[j];
            float* rowp = enc + (size_t)(n0 + j) * 1024;
            if (t < 255) {
                int k0 = 2 + t * 4;
                f32x4 v;
                v.x = (k0 == idx) ? 1.f : 0.f;
                v.y = (k0 + 1 == idx) ? 1.f : 0.f;
                v.z = (k0 + 2 == idx) ? 1.f : 0.f;
                v.w = (k0 + 3 == idx) ? 1.f : 0.f;
                __builtin_nontemporal_store(v, (f32x4*)(rowp + k0));
            } else {
                f32x2 hd, tl;
                hd.x = (0 == idx) ? 1.f : 0.f;
                hd.y = (1 == idx) ? 1.f : 0.f;
                tl.x = (1022 == idx) ? 1.f : 0.f;
                tl.y = (1023 == idx) ? 1.f : 0.f;
                __builtin_nontemporal_store(hd, (f32x2*)rowp);
                __builtin_nontemporal_store(tl, (f32x2*)(rowp + 1022));
            }
        }
    }

    // ---- loss reduction ----
#pragma unroll
    for (int off = 32; off >= 1; off >>= 1) ls += __shfl_down(ls, off);
    if (lane == 0) wsum[w] = ls;
    __syncthreads();
    if (t == 0) {
        float tot = wsum[0] + wsum[1] + wsum[2] + wsum[3];
        if constexpr (PASS == 0) {
            atomicAdd(lossacc, tot);
        } else {
            asm volatile("" ::"v"(tot));  // keep chain live, no side effect
        }
    }
}

// ---------------------------------------------------------------------------
// Kernel E: finalize loss + perplexity; also writes the 192 deferred enc rows
// (they alias cbb during fused_vq; safe now by stream ordering). 192 blocks.
// ---------------------------------------------------------------------------
__global__ __launch_bounds__(256) void finalize_kernel(const int* __restrict__ counts,
                                                       const float* __restrict__ lossacc,
                                                       const int* __restrict__ indices,
                                                       float* __restrict__ enc,
                                                       float* __restrict__ out_scalars) {
    const int t = threadIdx.x;
    // deferred one-hot row
    {
        int nrow = blockIdx.x;  // 0..191
        int idx = indices[nrow];
        float* rowp = enc + (size_t)nrow * 1024;
        if (t < 255) {
            int k0 = 2 + t * 4;
            f32x4 v;
            v.x = (k0 == idx) ? 1.f : 0.f;
            v.y = (k0 + 1 == idx) ? 1.f : 0.f;
            v.z = (k0 + 2 == idx) ? 1.f : 0.f;
            v.w = (k0 + 3 == idx) ? 1.f : 0.f;
            __builtin_nontemporal_store(v, (f32x4*)(rowp + k0));
        } else {
            f32x2 hd, tl;
            hd.x = (0 == idx) ? 1.f : 0.f;
            hd.y = (1 == idx) ? 1.f : 0.f;
            tl.x = (1022 == idx) ? 1.f : 0.f;
            tl.y = (1023 == idx) ? 1.f : 0.f;
            __builtin_nontemporal_store(hd, (f32x2*)rowp);
            __builtin_nontemporal_store(tl, (f32x2*)(rowp + 1022));
        }
    }
    if (blockIdx.x != 0) return;
    float s = 0.f;
#pragma unroll
    for (int i = 0; i < 4; i++) {
        int k = t + i * 256;
        float p = (float)counts[k] * (1.0f / 32768.0f);
        s += p * logf(p + 1e-10f);
    }
#pragma unroll
    for (int off = 32; off >= 1; off >>= 1) s += __shfl_down(s, off);
    __shared__ float red[4];
    if ((t & 63) == 0) red[t >> 6] = s;
    __syncthreads();
    if (t == 0) {
        float tot = red[0] + red[1] + red[2] + red[3];
        out_scalars[0] = 1.25f * (lossacc[0] * (1.0f / 8388608.0f));  // q + beta*e
        out_scalars[1] = expf(-tot);                                  // perplexity
    }
}

// ---------------------------------------------------------------------------
extern "C" void kernel_launch(void* const* d_in, const int* in_sizes, int n_in,
                              void* d_out, int out_size, void* d_ws, size_t ws_size,
                              hipStream_t stream) {
    const float* z = (const float*)d_in[0];   // [32,256,32,32]
    const float* cb = (const float*)d_in[1];  // [1024,256]
    float* out = (float*)d_out;
    char* wsb = (char*)d_ws;

    float* cnorm = (float*)wsb;             // 1024 f32
    int* counts = (int*)(wsb + 4096);       // 1024 i32
    float* lossacc = (float*)(wsb + 8192);  // 1 f32
    int* indices = (int*)(wsb + 16384);     // 32768 i32

    float* quant = out;             // [0, 8388608)
    float* scal = out + N_ELEM;     // loss @ +0, perplexity @ +1
    float* enc = out + N_ELEM + 2;  // [8388610, +33554432)

    // cbb (512KB, bf16 fragment order) aliases enc rows 0..128; those rows
    // are deferred to finalize_kernel (see fused_vq comment).
    unsigned short* cbb = (unsigned short*)(out + 8388612);  // 16B-aligned

    hipLaunchKernelGGL(prep_kernel, dim3(128), dim3(256), 0, stream, cb, cbb,
                       cnorm, counts, lossacc);
    hipLaunchKernelGGL((fused_vq<0>), dim3(512), dim3(256), 0, stream, z, cbb,
                       cnorm, cb, indices, counts, quant, enc, lossacc);
    // INSTRUMENT: idempotent second pass; dur_us delta vs round 3 == T(fused_vq)
    hipLaunchKernelGGL((fused_vq<1>), dim3(512), dim3(256), 0, stream, z, cbb,
                       cnorm, cb, indices, counts, quant, enc, lossacc);
    hipLaunchKernelGGL(finalize_kernel, dim3(192), dim3(256), 0, stream, counts,
                       lossacc, indices, enc, scal);
}

// Round 6
// 248.739 us; speedup vs baseline: 1.3283x; 1.3283x over previous
//
#include <hip/hip_runtime.h>
#include <hip/hip_bf16.h>

#define D_DIM 256
#define K_CODES 1024
#define HW 1024
#define N_VEC 32768
#define N_ELEM 8388608ull

typedef __attribute__((ext_vector_type(8))) short bf16x8;
typedef __attribute__((ext_vector_type(4))) float f32x4;
typedef __attribute__((ext_vector_type(2))) float f32x2;

static __device__ __forceinline__ unsigned short f2bf(float x) {
    union { __hip_bfloat16 h; unsigned short u; } cvt;
    cvt.h = __float2bfloat16(x);
    return cvt.u;
}

// ---------------------------------------------------------------------------
// Kernel A (fused prep): codebook -> bf16 B-fragment order + codebook norms
// + zero counts/lossacc. 128 blocks x 256.
// ---------------------------------------------------------------------------
__global__ __launch_bounds__(256) void prep_kernel(const float* __restrict__ cb,
                                                   unsigned short* __restrict__ cbb,
                                                   float* __restrict__ cnorm,
                                                   int* __restrict__ counts,
                                                   float* __restrict__ lossacc) {
    int slot = blockIdx.x * 256 + threadIdx.x;  // 0 .. 32767
    // --- cbprep: fragment-order bf16 codebook ---
    {
        int lane = slot & 63;
        int dchunk = (slot >> 6) & 7;
        int ktile = slot >> 9;
        int code = ktile * 16 + (lane & 15);
        int d0 = dchunk * 32 + (lane >> 4) * 8;
        const float4* src = (const float4*)(cb + (size_t)code * D_DIM + d0);
        float4 v0 = src[0], v1 = src[1];
        int4 o;
        o.x = f2bf(v0.x) | ((unsigned)f2bf(v0.y) << 16);
        o.y = f2bf(v0.z) | ((unsigned)f2bf(v0.w) << 16);
        o.z = f2bf(v1.x) | ((unsigned)f2bf(v1.y) << 16);
        o.w = f2bf(v1.z) | ((unsigned)f2bf(v1.w) << 16);
        *(int4*)(cbb + (size_t)slot * 8) = o;
    }
    // --- cnorm (8 lanes per code) + zero counts/lossacc ---
    if (slot < 8192) {
        if (slot < K_CODES) counts[slot] = 0;
        if (slot == K_CODES) lossacc[0] = 0.f;
        int k = slot >> 3;
        int part = slot & 7;
        const float4* row = (const float4*)(cb + (size_t)k * D_DIM + part * 32);
        float s = 0.f;
#pragma unroll
        for (int i = 0; i < 8; i++) {
            float4 v = row[i];
            s = fmaf(v.x, v.x, s);
            s = fmaf(v.y, v.y, s);
            s = fmaf(v.z, v.z, s);
            s = fmaf(v.w, v.w, s);
        }
        s += __shfl_xor(s, 1);
        s += __shfl_xor(s, 2);
        s += __shfl_xor(s, 4);
        if (part == 0) cnorm[k] = s;
    }
}

// ---------------------------------------------------------------------------
// Kernel B (FUSED): argmin via bf16 MFMA + quantize/STE + loss + one-hot enc.
// Structure identical to round 3. ONE variable changed vs R3 (clean A/B):
// NONTEMPORAL dropped from z loads and out stores. Those access 64B
// HALF-LINE segments whose complementary half is touched by a different wave
// -> they need L2 allocate/merge (NT bypass risks z refetch + out RMW at
// HBM). NT is kept ONLY on the enc stores, which are full-line contiguous
// 128MB streams where cache bypass is correct.
// R5 instrumentation result: T(fused_vq) ~= 80us vs ~35us byte-roofline.
// ---------------------------------------------------------------------------
__global__ __launch_bounds__(256, 2) void fused_vq(const float* __restrict__ z,
                                                   const unsigned short* __restrict__ cbb,
                                                   const float* __restrict__ cnorm,
                                                   const float* __restrict__ cb,
                                                   int* __restrict__ indices,
                                                   int* __restrict__ counts,
                                                   float* __restrict__ out,
                                                   float* __restrict__ enc,
                                                   float* __restrict__ lossacc) {
    __shared__ unsigned short Bbuf[2][4 * 8 * 64 * 8];  // 2 x 32 KB
    __shared__ int bk[64];
    __shared__ float wsum[4];
    const int t = threadIdx.x;
    const int lane = t & 63;
    const int w = t >> 6;                // wave 0..3
    const int nt0 = blockIdx.x * 4 + w;  // wave owns ONE ntile
    const int row = lane & 15;
    const int dq = (lane >> 4) * 8;
    const int n = nt0 * 16 + row;  // this lane's z row
    const int b = n >> 10;
    const int hw = n & (HW - 1);

    // ---- prologue: load z f32 (kept in regs) + pack bf16 A fragments ----
    float zf[8][8];
    bf16x8 Ar[8];
#pragma unroll
    for (int dc = 0; dc < 8; dc++) {
        const float* src = z + (((size_t)(b * D_DIM + dc * 32 + dq)) << 10) + hw;
        union { bf16x8 v; unsigned short u[8]; } pk;
#pragma unroll
        for (int j = 0; j < 8; j++) {
            zf[dc][j] = src[(size_t)j << 10];  // plain load: L2 merges half-lines
            pk.u[j] = f2bf(zf[dc][j]);
        }
        Ar[dc] = pk.v;
    }

    // ---- async stage of chunk 0 ----
    {
        const unsigned int* g = (const unsigned int*)cbb;
        unsigned int* l = (unsigned int*)Bbuf[0];
#pragma unroll
        for (int p = 0; p < 8; p++) {
            int off = (p * 256 + t) * 4;
            __builtin_amdgcn_global_load_lds(
                (const __attribute__((address_space(1))) unsigned int*)(g + off),
                (__attribute__((address_space(3))) unsigned int*)(l + off), 16, 0, 0);
        }
    }

    float bestd[4];
    int bestk[4];
#pragma unroll
    for (int r = 0; r < 4; r++) { bestd[r] = 3.4e38f; bestk[r] = 0; }

    const int col = lane & 15;
    for (int c = 0; c < 16; c++) {
        const int cur = c & 1;
        __syncthreads();  // drains vmcnt -> Bbuf[cur] ready; all waves done with other buf
        if (c < 15) {
            const unsigned int* g = (const unsigned int*)(cbb + (size_t)(c + 1) * 16384);
            unsigned int* l = (unsigned int*)Bbuf[cur ^ 1];
#pragma unroll
            for (int p = 0; p < 8; p++) {
                int off = (p * 256 + t) * 4;
                __builtin_amdgcn_global_load_lds(
                    (const __attribute__((address_space(1))) unsigned int*)(g + off),
                    (__attribute__((address_space(3))) unsigned int*)(l + off), 16, 0, 0);
            }
        }
        const unsigned short* Bb = Bbuf[cur];
#pragma unroll
        for (int half = 0; half < 2; half++) {  // 2 ktiles at a time, bb = 64 VGPR
            bf16x8 bb[2][8];
#pragma unroll
            for (int kt2 = 0; kt2 < 2; kt2++)
#pragma unroll
                for (int dc = 0; dc < 8; dc++)
                    bb[kt2][dc] = *(const bf16x8*)
                        &Bb[(((half * 2 + kt2) * 8 + dc) * 64 + lane) * 8];
            f32x4 acc[2];
#pragma unroll
            for (int kt2 = 0; kt2 < 2; kt2++) acc[kt2] = (f32x4){0.f, 0.f, 0.f, 0.f};
#pragma unroll
            for (int dc = 0; dc < 8; dc++)
#pragma unroll
                for (int kt2 = 0; kt2 < 2; kt2++)
                    acc[kt2] = __builtin_amdgcn_mfma_f32_16x16x32_bf16(
                        Ar[dc], bb[kt2][dc], acc[kt2], 0, 0, 0);
            // running best (k ascending => first-min tiebreak)
#pragma unroll
            for (int kt2 = 0; kt2 < 2; kt2++) {
                int k = (c * 4 + half * 2 + kt2) * 16 + col;
                float cn = cnorm[k];
#pragma unroll
                for (int r = 0; r < 4; r++) {
                    float sc = fmaf(-2.0f, acc[kt2][r], cn);
                    if (sc < bestd[r]) { bestd[r] = sc; bestk[r] = k; }
                }
            }
        }
    }

    // ---- reduce across the 16 columns; stash winning codes in LDS ----
#pragma unroll
    for (int r = 0; r < 4; r++) {
        float dd = bestd[r];
        int kk = bestk[r];
#pragma unroll
        for (int off = 8; off >= 1; off >>= 1) {
            float d2 = __shfl_xor(dd, off);
            int k2 = __shfl_xor(kk, off);
            if (d2 < dd || (d2 == dd && k2 < kk)) { dd = d2; kk = k2; }
        }
        if ((lane & 15) == 0) {
            int nloc = w * 16 + (lane >> 4) * 4 + r;  // block-local n
            bk[nloc] = kk;
            indices[blockIdx.x * 64 + nloc] = kk;
            atomicAdd(&counts[kk], 1);
        }
    }
    __syncthreads();  // bk visible to all waves

    // ---- epilogue 1: quantize + STE output + loss (z still in VGPRs) ----
    const int mycode = bk[w * 16 + row];
    const float* crow = cb + (size_t)mycode * D_DIM;
    float* obase = out + (((size_t)b * D_DIM) << 10) + hw;
    float ls = 0.f;
#pragma unroll
    for (int dc = 0; dc < 8; dc++)
#pragma unroll
        for (int j = 0; j < 8; j++) {
            int d = dc * 32 + dq + j;
            float q = crow[d];
            float zv = zf[dc][j];
            float e = q - zv;
            obase[(size_t)d << 10] = zv + e;  // plain store: L2 merges half-lines
            ls = fmaf(e, e, ls);
        }

    // ---- epilogue 2: one-hot enc rows (skip rows <192: cbb alias, deferred) ----
    const int n0 = blockIdx.x * 64;
    if (n0 >= 192) {
#pragma unroll 4
        for (int j = 0; j < 64; j++) {
            int idx = bk[j];
            float* rowp = enc + (size_t)(n0 + j) * 1024;
            if (t < 255) {
                int k0 = 2 + t * 4;
                f32x4 v;
                v.x = (k0 == idx) ? 1.f : 0.f;
                v.y = (k0 + 1 == idx) ? 1.f : 0.f;
                v.z = (k0 + 2 == idx) ? 1.f : 0.f;
                v.w = (k0 + 3 == idx) ? 1.f : 0.f;
                __builtin_nontemporal_store(v, (f32x4*)(rowp + k0));
            } else {
                f32x2 hd, tl;
                hd.x = (0 == idx) ? 1.f : 0.f;
                hd.y = (1 == idx) ? 1.f : 0.f;
                tl.x = (1022 == idx) ? 1.f : 0.f;
                tl.y = (1023 == idx) ? 1.f : 0.f;
                __builtin_nontemporal_store(hd, (f32x2*)rowp);
                __builtin_nontemporal_store(tl, (f32x2*)(rowp + 1022));
            }
        }
    }

    // ---- loss reduction ----
#pragma unroll
    for (int off = 32; off >= 1; off >>= 1) ls += __shfl_down(ls, off);
    if (lane == 0) wsum[w] = ls;
    __syncthreads();
    if (t == 0) atomicAdd(lossacc, wsum[0] + wsum[1] + wsum[2] + wsum[3]);
}

// ---------------------------------------------------------------------------
// Kernel E: finalize loss + perplexity; also writes the 192 deferred enc rows
// (they alias cbb during fused_vq; safe now by stream ordering). 192 blocks.
// ---------------------------------------------------------------------------
__global__ __launch_bounds__(256) void finalize_kernel(const int* __restrict__ counts,
                                                       const float* __restrict__ lossacc,
                                                       const int* __restrict__ indices,
                                                       float* __restrict__ enc,
                                                       float* __restrict__ out_scalars) {
    const int t = threadIdx.x;
    // deferred one-hot row
    {
        int nrow = blockIdx.x;  // 0..191
        int idx = indices[nrow];
        float* rowp = enc + (size_t)nrow * 1024;
        if (t < 255) {
            int k0 = 2 + t * 4;
            f32x4 v;
            v.x = (k0 == idx) ? 1.f : 0.f;
            v.y = (k0 + 1 == idx) ? 1.f : 0.f;
            v.z = (k0 + 2 == idx) ? 1.f : 0.f;
            v.w = (k0 + 3 == idx) ? 1.f : 0.f;
            __builtin_nontemporal_store(v, (f32x4*)(rowp + k0));
        } else {
            f32x2 hd, tl;
            hd.x = (0 == idx) ? 1.f : 0.f;
            hd.y = (1 == idx) ? 1.f : 0.f;
            tl.x = (1022 == idx) ? 1.f : 0.f;
            tl.y = (1023 == idx) ? 1.f : 0.f;
            __builtin_nontemporal_store(hd, (f32x2*)rowp);
            __builtin_nontemporal_store(tl, (f32x2*)(rowp + 1022));
        }
    }
    if (blockIdx.x != 0) return;
    float s = 0.f;
#pragma unroll
    for (int i = 0; i < 4; i++) {
        int k = t + i * 256;
        float p = (float)counts[k] * (1.0f / 32768.0f);
        s += p * logf(p + 1e-10f);
    }
#pragma unroll
    for (int off = 32; off >= 1; off >>= 1) s += __shfl_down(s, off);
    __shared__ float red[4];
    if ((t & 63) == 0) red[t >> 6] = s;
    __syncthreads();
    if (t == 0) {
        float tot = red[0] + red[1] + red[2] + red[3];
        out_scalars[0] = 1.25f * (lossacc[0] * (1.0f / 8388608.0f));  // q + beta*e
        out_scalars[1] = expf(-tot);                                  // perplexity
    }
}

// ---------------------------------------------------------------------------
extern "C" void kernel_launch(void* const* d_in, const int* in_sizes, int n_in,
                              void* d_out, int out_size, void* d_ws, size_t ws_size,
                              hipStream_t stream) {
    const float* z = (const float*)d_in[0];   // [32,256,32,32]
    const float* cb = (const float*)d_in[1];  // [1024,256]
    float* out = (float*)d_out;
    char* wsb = (char*)d_ws;

    float* cnorm = (float*)wsb;             // 1024 f32
    int* counts = (int*)(wsb + 4096);       // 1024 i32
    float* lossacc = (float*)(wsb + 8192);  // 1 f32
    int* indices = (int*)(wsb + 16384);     // 32768 i32

    float* quant = out;             // [0, 8388608)
    float* scal = out + N_ELEM;     // loss @ +0, perplexity @ +1
    float* enc = out + N_ELEM + 2;  // [8388610, +33554432)

    // cbb (512KB, bf16 fragment order) aliases enc rows 0..128; those rows
    // are deferred to finalize_kernel (see fused_vq comment).
    unsigned short* cbb = (unsigned short*)(out + 8388612);  // 16B-aligned

    hipLaunchKernelGGL(prep_kernel, dim3(128), dim3(256), 0, stream, cb, cbb,
                       cnorm, counts, lossacc);
    hipLaunchKernelGGL(fused_vq, dim3(512), dim3(256), 0, stream, z, cbb,
                       cnorm, cb, indices, counts, quant, enc, lossacc);
    hipLaunchKernelGGL(finalize_kernel, dim3(192), dim3(256), 0, stream, counts,
                       lossacc, indices, enc, scal);
}